// Round 14
// baseline (84.780 us; speedup 1.0000x reference)
//
// GCN2 on MI355X — r13: revert to 8-deep MLP (16-deep cost 3us, r13 lesson); degree-binned
// node order[] from p2group kills agg wave-divergence; k_zero -> hipMemsetAsync node.
#include <hip/hip_runtime.h>
#include <hip/hip_fp16.h>
#include <math.h>

#define N_NODES 50000
#define N_EDGES 800000
#define D_FEAT 64

#define NBUCKET 196            // bucket = dst>>8 ; max 49999>>8 = 195
#define PART_BLOCKS 391        // 391*2048 = 800768 >= E
#define PART_EPB 2048
#define BCAP 6144              // per-bucket capacity; mean 4082, sigma 64

#define GEMM_BLOCKS (N_NODES / 16)          // 3125 exact
#define AGG_UNITS 1568                      // 1568*32 = 50176 node slots (= N_PAD)
#define N_PAD (NBUCKET * 256)               // 50176

typedef float v2f __attribute__((ext_vector_type(2)));

// ---------------- fp8 helpers (OCP e4m3, hw cvt on gfx950) ----------------

__device__ __forceinline__ unsigned pack_fp8x4(float a, float b, float c, float d) {
    unsigned w = 0;
    w = __builtin_amdgcn_cvt_pk_fp8_f32(a, b, w, false);   // bytes 0-1
    w = __builtin_amdgcn_cvt_pk_fp8_f32(c, d, w, true);    // bytes 2-3
    return w;
}

__device__ __forceinline__ void addf8(float acc[8], uint2 r) {
    v2f f0 = __builtin_amdgcn_cvt_pk_f32_fp8(r.x, false);
    v2f f1 = __builtin_amdgcn_cvt_pk_f32_fp8(r.x, true);
    v2f f2 = __builtin_amdgcn_cvt_pk_f32_fp8(r.y, false);
    v2f f3 = __builtin_amdgcn_cvt_pk_f32_fp8(r.y, true);
    acc[0] += f0[0]; acc[1] += f0[1];
    acc[2] += f1[0]; acc[3] += f1[1];
    acc[4] += f2[0]; acc[5] += f2[1];
    acc[6] += f3[0]; acc[7] += f3[1];
}

// ---------------- CSR build ----------------

// register-staged bucket partition: 8 packed words/thread
__global__ __launch_bounds__(256) void k_part(const int* __restrict__ src,
                                              const int* __restrict__ dst,
                                              int* __restrict__ gcount,
                                              unsigned* __restrict__ ebuf) {
    __shared__ int cnt[NBUCKET];
    int tid = threadIdx.x;
    for (int i = tid; i < NBUCKET; i += 256) cnt[i] = 0;
    __syncthreads();
    int e0 = blockIdx.x * PART_EPB;
    unsigned pw[8];
    #pragma unroll
    for (int u = 0; u < 8; ++u) {
        int e = e0 + u * 256 + tid;
        pw[u] = 0xFFFFFFFFu;                 // sentinel bucket 255 >= NBUCKET
        if (e < N_EDGES) {
            int d = dst[e];
            pw[u] = (unsigned)src[e] | ((unsigned)(d & 255) << 16) | ((unsigned)(d >> 8) << 24);
            atomicAdd(&cnt[d >> 8], 1);
        }
    }
    __syncthreads();
    for (int i = tid; i < NBUCKET; i += 256)
        cnt[i] = atomicAdd(&gcount[i], cnt[i]);      // cnt[i] := bucket-local base
    __syncthreads();
    #pragma unroll
    for (int u = 0; u < 8; ++u) {
        unsigned p = pw[u];
        int b = p >> 24;
        if (b < NBUCKET) {
            int slot = atomicAdd(&cnt[b], 1);
            if (slot < BCAP) ebuf[(size_t)b * BCAP + slot] = p;
        }
    }
}

// per-bucket exact grouping + degree-binned node order, 512 threads
__global__ __launch_bounds__(512) void k_p2group(const unsigned* __restrict__ ebuf,
                                                 const int* __restrict__ gcount,
                                                 int* __restrict__ rowbeg,
                                                 int* __restrict__ rowdeg,
                                                 ushort* __restrict__ colsrc,
                                                 float* __restrict__ dinv,
                                                 int* __restrict__ order) {
    __shared__ unsigned eloc[BCAP];
    __shared__ int hist[256];
    __shared__ int sh[256];
    __shared__ int bin2[64];
    int tid = threadIdx.x;
    int b = blockIdx.x;
    int cnt = gcount[b]; if (cnt > BCAP) cnt = BCAP;
    if (tid < 256) hist[tid] = 0;
    if (tid >= 256 && tid < 320) bin2[tid - 256] = 0;
    __syncthreads();
    for (int i = tid; i < cnt; i += 512) {
        unsigned p = ebuf[(size_t)b * BCAP + i];
        eloc[i] = p;
        atomicAdd(&hist[(p >> 16) & 255], 1);
    }
    __syncthreads();
    int v = (tid < 256) ? hist[tid] : 0;
    if (tid < 256) sh[tid] = v;
    __syncthreads();
    #pragma unroll
    for (int off = 1; off < 256; off <<= 1) {
        int t = (tid >= off && tid < 256) ? sh[tid - off] : 0;
        __syncthreads();
        if (tid < 256) sh[tid] += t;
        __syncthreads();
    }
    int bin = (v < 63) ? v : 63;
    if (tid < 256) {
        int binoff = sh[tid] - v;
        int node = b * 256 + tid;
        rowbeg[node] = b * BCAP + binoff;
        rowdeg[node] = v;
        dinv[node] = rsqrtf((float)(v + 1));
        hist[tid] = binoff;                    // reuse as edge-scatter cursor
        atomicAdd(&bin2[bin], 1);              // degree histogram (64 bins)
    }
    __syncthreads();
    if (tid == 0) {                            // exclusive scan of 64 bins (serial, cheap)
        int run = 0;
        #pragma unroll
        for (int i = 0; i < 64; ++i) { int c = bin2[i]; bin2[i] = run; run += c; }
    }
    __syncthreads();
    if (tid < 256) {                           // degree-sorted node order within bucket
        int r = atomicAdd(&bin2[bin], 1);
        order[b * 256 + r] = b * 256 + tid;
    }
    __syncthreads();
    for (int i = tid; i < cnt; i += 512) {
        unsigned p = eloc[i];
        int slot = b * BCAP + atomicAdd(&hist[(p >> 16) & 255], 1);
        colsrc[slot] = (ushort)(p & 0xFFFFu);
    }
}

// ---------------- GEMM1: hm1' = (x@W1)*dinv -> fp8 rows (64B) ----------------

__global__ __launch_bounds__(256) void k_gemm_f32(const float* __restrict__ X,
                                                  const float* __restrict__ W,
                                                  const float* __restrict__ dinv,
                                                  unsigned* __restrict__ out8) {
    __shared__ float Wl[64][64];
    int tid = threadIdx.x;
    {
        const float4* Wv = (const float4*)W;
        float4* Wlv = (float4*)&Wl[0][0];
        #pragma unroll
        for (int i = 0; i < 4; ++i) Wlv[tid + 256 * i] = Wv[tid + 256 * i];
    }
    __syncthreads();
    int r = blockIdx.x * 16 + (tid >> 4);
    int c0 = (tid & 15) << 2;
    const float4* xrow = (const float4*)(X + (size_t)r * D_FEAT);
    float ax = 0.f, ay = 0.f, az = 0.f, aw = 0.f;
    #pragma unroll
    for (int k4 = 0; k4 < 16; ++k4) {
        float4 xv = xrow[k4];
        #pragma unroll
        for (int j = 0; j < 4; ++j) {
            float xs = (j == 0) ? xv.x : (j == 1) ? xv.y : (j == 2) ? xv.z : xv.w;
            const float4 wv = *(const float4*)&Wl[4 * k4 + j][c0];
            ax += xs * wv.x; ay += xs * wv.y; az += xs * wv.z; aw += xs * wv.w;
        }
    }
    float sc = dinv[r];
    out8[r * 16 + (c0 >> 2)] = pack_fp8x4(ax * sc, ay * sc, az * sc, aw * sc);
}

// ---------------- aggregation core: 8 lanes/node, fp8 rows, 8-deep MLP ----------------

__device__ __forceinline__ void agg_core(const unsigned char* __restrict__ hm,
                                         const ushort* __restrict__ colsrc,
                                         int beg, int deg, int o, float acc[8]) {
    const uint2* hv = (const uint2*)hm;     // row = 8 uint2 (64 B)
    int j = 0;
    for (; j + 8 <= deg; j += 8) {
        int s[8]; uint2 r[8];
        #pragma unroll
        for (int u = 0; u < 8; ++u) s[u] = colsrc[beg + j + u];
        #pragma unroll
        for (int u = 0; u < 8; ++u) r[u] = hv[(size_t)s[u] * 8 + o];
        #pragma unroll
        for (int u = 0; u < 8; ++u) addf8(acc, r[u]);
    }
    if (j + 4 <= deg) {
        int s[4]; uint2 r[4];
        #pragma unroll
        for (int u = 0; u < 4; ++u) s[u] = colsrc[beg + j + u];
        #pragma unroll
        for (int u = 0; u < 4; ++u) r[u] = hv[(size_t)s[u] * 8 + o];
        #pragma unroll
        for (int u = 0; u < 4; ++u) addf8(acc, r[u]);
        j += 4;
    }
    for (; j < deg; ++j) {
        int s = colsrc[beg + j];
        addf8(acc, hv[(size_t)s * 8 + o]);
    }
}

// ---- layer-1 agg + ReLU + in-register GEMM2: hm2' = (relu(di*sum+b1)@W2)*di -> fp8 ----

__global__ __launch_bounds__(256) void k_agg1_g2(const unsigned char* __restrict__ hm,
                                                 const int* __restrict__ rowbeg,
                                                 const int* __restrict__ rowdeg,
                                                 const ushort* __restrict__ colsrc,
                                                 const float* __restrict__ dinv,
                                                 const int* __restrict__ order,
                                                 const float* __restrict__ b1,
                                                 const float* __restrict__ W2,
                                                 unsigned char* __restrict__ outp) {
    __shared__ float Wl[64][64];
    {
        const float4* Wv = (const float4*)W2;
        float4* Wlv = (float4*)&Wl[0][0];
        #pragma unroll
        for (int i = 0; i < 4; ++i) Wlv[threadIdx.x + 256 * i] = Wv[threadIdx.x + 256 * i];
    }
    __syncthreads();
    int lane = threadIdx.x & 63;
    int wid = threadIdx.x >> 6;
    int node = order[(blockIdx.x * 4 + wid) * 8 + (lane >> 3)];   // degree-sorted slot
    int o = lane & 7;
    if (node < N_NODES) {
        float acc[8];
        #pragma unroll
        for (int i = 0; i < 8; ++i) acc[i] = 0.f;
        const uint2* hv = (const uint2*)hm;
        addf8(acc, hv[(size_t)node * 8 + o]);               // self (pre-scaled)
        agg_core(hm, colsrc, rowbeg[node], rowdeg[node], o, acc);
        float di = dinv[node];
        const float4* b4 = (const float4*)b1;
        float4 bl = b4[o * 2], bh = b4[o * 2 + 1];
        float h1[8];
        h1[0] = fmaxf(di * acc[0] + bl.x, 0.f);
        h1[1] = fmaxf(di * acc[1] + bl.y, 0.f);
        h1[2] = fmaxf(di * acc[2] + bl.z, 0.f);
        h1[3] = fmaxf(di * acc[3] + bl.w, 0.f);
        h1[4] = fmaxf(di * acc[4] + bh.x, 0.f);
        h1[5] = fmaxf(di * acc[5] + bh.y, 0.f);
        h1[6] = fmaxf(di * acc[6] + bh.z, 0.f);
        h1[7] = fmaxf(di * acc[7] + bh.w, 0.f);
        float oa[8];
        #pragma unroll
        for (int i = 0; i < 8; ++i) oa[i] = 0.f;
        int gbase = lane & 56;
        #pragma unroll
        for (int g = 0; g < 8; ++g) {
            #pragma unroll
            for (int j = 0; j < 8; ++j) {
                float hk = __shfl(h1[j], gbase | g, 64);    // h1[g*8+j] of this node
                const float4 w0 = *(const float4*)&Wl[g * 8 + j][o * 8];
                const float4 w1 = *(const float4*)&Wl[g * 8 + j][o * 8 + 4];
                oa[0] += hk * w0.x; oa[1] += hk * w0.y;
                oa[2] += hk * w0.z; oa[3] += hk * w0.w;
                oa[4] += hk * w1.x; oa[5] += hk * w1.y;
                oa[6] += hk * w1.z; oa[7] += hk * w1.w;
            }
        }
        uint2 st;
        st.x = pack_fp8x4(oa[0] * di, oa[1] * di, oa[2] * di, oa[3] * di);
        st.y = pack_fp8x4(oa[4] * di, oa[5] * di, oa[6] * di, oa[7] * di);
        *(uint2*)(outp + (size_t)node * D_FEAT + o * 8) = st;
    }
}

// ---- layer-2 agg + b2 + ReLU + dot(Wfc) + block partial sum ----

__global__ __launch_bounds__(256) void k_agg2_dot(const unsigned char* __restrict__ hm,
                                                  const int* __restrict__ rowbeg,
                                                  const int* __restrict__ rowdeg,
                                                  const ushort* __restrict__ colsrc,
                                                  const float* __restrict__ dinv,
                                                  const int* __restrict__ order,
                                                  const float* __restrict__ bias,
                                                  const float* __restrict__ Wfc,
                                                  float* __restrict__ partials) {
    __shared__ float red[4];
    int lane = threadIdx.x & 63;
    int wid = threadIdx.x >> 6;
    int node = order[(blockIdx.x * 4 + wid) * 8 + (lane >> 3)];
    int o = lane & 7;
    float s = 0.f;
    if (node < N_NODES) {
        float acc[8];
        #pragma unroll
        for (int i = 0; i < 8; ++i) acc[i] = 0.f;
        const uint2* hv = (const uint2*)hm;
        addf8(acc, hv[(size_t)node * 8 + o]);
        agg_core(hm, colsrc, rowbeg[node], rowdeg[node], o, acc);
        float di = dinv[node];
        const float4* b4 = (const float4*)bias;
        const float4* w4 = (const float4*)Wfc;
        float4 bl = b4[o * 2], bh = b4[o * 2 + 1];
        float4 wl = w4[o * 2], wh = w4[o * 2 + 1];
        s  = fmaxf(di * acc[0] + bl.x, 0.f) * wl.x;
        s += fmaxf(di * acc[1] + bl.y, 0.f) * wl.y;
        s += fmaxf(di * acc[2] + bl.z, 0.f) * wl.z;
        s += fmaxf(di * acc[3] + bl.w, 0.f) * wl.w;
        s += fmaxf(di * acc[4] + bh.x, 0.f) * wh.x;
        s += fmaxf(di * acc[5] + bh.y, 0.f) * wh.y;
        s += fmaxf(di * acc[6] + bh.z, 0.f) * wh.z;
        s += fmaxf(di * acc[7] + bh.w, 0.f) * wh.w;
    }
    #pragma unroll
    for (int m = 1; m < 64; m <<= 1) s += __shfl_xor(s, m, 64);
    if (lane == 0) red[wid] = s;
    __syncthreads();
    if (threadIdx.x == 0) partials[blockIdx.x] = red[0] + red[1] + red[2] + red[3];
}

__global__ __launch_bounds__(256) void k_final(const float* __restrict__ partials,
                                               const float* __restrict__ bfc,
                                               float* __restrict__ out) {
    __shared__ float red[4];
    float s = 0.0f;
    for (int i = threadIdx.x; i < AGG_UNITS; i += 256) s += partials[i];
    #pragma unroll
    for (int off = 32; off > 0; off >>= 1) s += __shfl_down(s, off, 64);
    if ((threadIdx.x & 63) == 0) red[threadIdx.x >> 6] = s;
    __syncthreads();
    if (threadIdx.x == 0) {
        float t = red[0] + red[1] + red[2] + red[3];
        float z = t / (float)N_NODES + bfc[0];
        out[0] = 1.0f / (1.0f + expf(-z));
    }
}

// ---------------- launcher ----------------

extern "C" void kernel_launch(void* const* d_in, const int* in_sizes, int n_in,
                              void* d_out, int out_size, void* d_ws, size_t ws_size,
                              hipStream_t stream) {
    const float* x   = (const float*)d_in[0];
    const int*   ei  = (const int*)d_in[1];
    const int*   src = ei;               // edge_index[0]
    const int*   dst = ei + N_EDGES;     // edge_index[1]
    const float* W1  = (const float*)d_in[2];
    const float* b1  = (const float*)d_in[3];
    const float* W2  = (const float*)d_in[4];
    const float* b2  = (const float*)d_in[5];
    const float* Wfc = (const float*)d_in[6];
    const float* bfc = (const float*)d_in[7];
    float* out = (float*)d_out;

    char* ws = (char*)d_ws;
    size_t off = 0;
    auto alloc = [&](size_t bytes) -> char* {
        char* p = ws + off;
        off += (bytes + 255) & ~(size_t)255;
        return p;
    };
    int*           gcount   = (int*)alloc((size_t)NBUCKET * 4);
    unsigned*      ebuf     = (unsigned*)alloc((size_t)NBUCKET * BCAP * 4);  // 4.8 MB
    ushort*        colsrc   = (ushort*)alloc((size_t)NBUCKET * BCAP * 2);    // 2.4 MB
    int*           rowbeg   = (int*)alloc((size_t)N_PAD * 4);
    int*           rowdeg   = (int*)alloc((size_t)N_PAD * 4);
    float*         dinv     = (float*)alloc((size_t)N_PAD * 4);
    int*           order    = (int*)alloc((size_t)N_PAD * 4);
    float*         partials = (float*)alloc((size_t)AGG_UNITS * 4);
    unsigned char* bufA     = (unsigned char*)alloc((size_t)N_NODES * D_FEAT);  // fp8
    unsigned char* bufB     = (unsigned char*)alloc((size_t)N_NODES * D_FEAT);  // fp8

    // CSR build (gcount zeroed by graph memset node — cheaper than a kernel)
    hipMemsetAsync(gcount, 0, (size_t)NBUCKET * 4, stream);
    k_part     <<<PART_BLOCKS, 256, 0, stream>>>(src, dst, gcount, ebuf);
    k_p2group  <<<NBUCKET,     512, 0, stream>>>(ebuf, gcount, rowbeg, rowdeg, colsrc, dinv, order);

    // layer 1 GEMM: hm1' = (x@W1)*dinv (fp8)
    k_gemm_f32 <<<GEMM_BLOCKS, 256, 0, stream>>>(x, W1, dinv, (unsigned*)bufA);

    // layer-1 agg + relu + fused layer-2 GEMM -> fp8 (degree-sorted node order)
    k_agg1_g2  <<<AGG_UNITS,   256, 0, stream>>>(bufA, rowbeg, rowdeg, colsrc, dinv, order, b1, W2, bufB);

    // layer-2 agg + b2 + relu + dot(Wfc) + partial mean
    k_agg2_dot <<<AGG_UNITS,   256, 0, stream>>>(bufB, rowbeg, rowdeg, colsrc, dinv, order, b2, Wfc, partials);

    // final: sigmoid(mean + bfc)
    k_final    <<<1,           256, 0, stream>>>(partials, bfc, out);
}

// Round 15
// 80.568 us; speedup vs baseline: 1.0523x; 1.0523x over previous
//
// GCN2 on MI355X — r14: exact round-10 config (proven 80.6us best) with k_zero kernel
// replaced by a hipMemsetAsync graph node. All r12-r14 experiments reverted (all regressed).
#include <hip/hip_runtime.h>
#include <hip/hip_fp16.h>
#include <math.h>

#define N_NODES 50000
#define N_EDGES 800000
#define D_FEAT 64

#define NBUCKET 196            // bucket = dst>>8 ; max 49999>>8 = 195
#define PART_BLOCKS 196
#define PART_EPB 4096          // 196*4096 = 802816 >= E
#define BCAP 6144              // per-bucket capacity; mean 4082, sigma 64

#define GEMM_BLOCKS (N_NODES / 16)          // 3125 exact
#define AGG_UNITS 1568                      // 1568*32 = 50176 node slots (>= 50000)
#define N_PAD (NBUCKET * 256)               // 50176

typedef float v2f __attribute__((ext_vector_type(2)));

// ---------------- fp8 helpers (OCP e4m3, hw cvt on gfx950) ----------------

__device__ __forceinline__ unsigned pack_fp8x4(float a, float b, float c, float d) {
    unsigned w = 0;
    w = __builtin_amdgcn_cvt_pk_fp8_f32(a, b, w, false);   // bytes 0-1
    w = __builtin_amdgcn_cvt_pk_fp8_f32(c, d, w, true);    // bytes 2-3
    return w;
}

__device__ __forceinline__ void addf8(float acc[8], uint2 r) {
    v2f f0 = __builtin_amdgcn_cvt_pk_f32_fp8(r.x, false);
    v2f f1 = __builtin_amdgcn_cvt_pk_f32_fp8(r.x, true);
    v2f f2 = __builtin_amdgcn_cvt_pk_f32_fp8(r.y, false);
    v2f f3 = __builtin_amdgcn_cvt_pk_f32_fp8(r.y, true);
    acc[0] += f0[0]; acc[1] += f0[1];
    acc[2] += f1[0]; acc[3] += f1[1];
    acc[4] += f2[0]; acc[5] += f2[1];
    acc[6] += f3[0]; acc[7] += f3[1];
}

// ---------------- CSR build: partition + exact LDS grouping ----------------

__global__ __launch_bounds__(256) void k_part(const int* __restrict__ src,
                                              const int* __restrict__ dst,
                                              int* __restrict__ gcount,
                                              unsigned* __restrict__ ebuf) {
    __shared__ unsigned eloc[PART_EPB];
    __shared__ int cnt[NBUCKET];
    int tid = threadIdx.x;
    for (int i = tid; i < NBUCKET; i += 256) cnt[i] = 0;
    __syncthreads();
    int e0 = blockIdx.x * PART_EPB;
    int n = N_EDGES - e0; if (n > PART_EPB) n = PART_EPB;
    for (int k = tid; k < n; k += 256) {
        int e = e0 + k;
        int d = dst[e];
        eloc[k] = (unsigned)src[e] | ((unsigned)(d & 255) << 16) | ((unsigned)(d >> 8) << 24);
        atomicAdd(&cnt[d >> 8], 1);
    }
    __syncthreads();
    for (int i = tid; i < NBUCKET; i += 256)
        cnt[i] = atomicAdd(&gcount[i], cnt[i]);      // cnt[i] := bucket-local base
    __syncthreads();
    for (int k = tid; k < n; k += 256) {
        unsigned p = eloc[k];
        int b = p >> 24;
        int slot = atomicAdd(&cnt[b], 1);
        if (slot < BCAP) ebuf[(size_t)b * BCAP + slot] = p;
    }
}

__global__ __launch_bounds__(256) void k_p2group(const unsigned* __restrict__ ebuf,
                                                 const int* __restrict__ gcount,
                                                 int* __restrict__ rowbeg,
                                                 int* __restrict__ rowdeg,
                                                 ushort* __restrict__ colsrc,
                                                 float* __restrict__ dinv) {
    __shared__ unsigned eloc[BCAP];
    __shared__ int hist[256];
    __shared__ int sh[256];
    int tid = threadIdx.x;
    int b = blockIdx.x;
    int cnt = gcount[b]; if (cnt > BCAP) cnt = BCAP;
    hist[tid] = 0;
    __syncthreads();
    for (int i = tid; i < cnt; i += 256) {
        unsigned p = ebuf[(size_t)b * BCAP + i];
        eloc[i] = p;
        atomicAdd(&hist[(p >> 16) & 255], 1);
    }
    __syncthreads();
    int v = hist[tid];
    sh[tid] = v;
    __syncthreads();
    #pragma unroll
    for (int off = 1; off < 256; off <<= 1) {
        int t = (tid >= off) ? sh[tid - off] : 0;
        __syncthreads();
        sh[tid] += t;
        __syncthreads();
    }
    int binoff = sh[tid] - v;
    int node = b * 256 + tid;
    rowbeg[node] = b * BCAP + binoff;
    rowdeg[node] = v;
    dinv[node] = rsqrtf((float)(v + 1));
    hist[tid] = binoff;
    __syncthreads();
    for (int i = tid; i < cnt; i += 256) {
        unsigned p = eloc[i];
        int slot = b * BCAP + atomicAdd(&hist[(p >> 16) & 255], 1);
        colsrc[slot] = (ushort)(p & 0xFFFFu);
    }
}

// ---------------- GEMM1: hm1' = (x@W1)*dinv -> fp8 rows (64B) ----------------

__global__ __launch_bounds__(256) void k_gemm_f32(const float* __restrict__ X,
                                                  const float* __restrict__ W,
                                                  const float* __restrict__ dinv,
                                                  unsigned* __restrict__ out8) {
    __shared__ float Wl[64][64];
    int tid = threadIdx.x;
    {
        const float4* Wv = (const float4*)W;
        float4* Wlv = (float4*)&Wl[0][0];
        #pragma unroll
        for (int i = 0; i < 4; ++i) Wlv[tid + 256 * i] = Wv[tid + 256 * i];
    }
    __syncthreads();
    int r = blockIdx.x * 16 + (tid >> 4);
    int c0 = (tid & 15) << 2;
    const float4* xrow = (const float4*)(X + (size_t)r * D_FEAT);
    float ax = 0.f, ay = 0.f, az = 0.f, aw = 0.f;
    #pragma unroll
    for (int k4 = 0; k4 < 16; ++k4) {
        float4 xv = xrow[k4];
        #pragma unroll
        for (int j = 0; j < 4; ++j) {
            float xs = (j == 0) ? xv.x : (j == 1) ? xv.y : (j == 2) ? xv.z : xv.w;
            const float4 wv = *(const float4*)&Wl[4 * k4 + j][c0];
            ax += xs * wv.x; ay += xs * wv.y; az += xs * wv.z; aw += xs * wv.w;
        }
    }
    float sc = dinv[r];
    out8[r * 16 + (c0 >> 2)] = pack_fp8x4(ax * sc, ay * sc, az * sc, aw * sc);
}

// ---------------- aggregation core: 8 lanes/node, fp8 rows, 8-deep MLP ----------------

__device__ __forceinline__ void agg_core(const unsigned char* __restrict__ hm,
                                         const ushort* __restrict__ colsrc,
                                         int beg, int deg, int o, float acc[8]) {
    const uint2* hv = (const uint2*)hm;     // row = 8 uint2 (64 B)
    int j = 0;
    for (; j + 8 <= deg; j += 8) {
        int s[8]; uint2 r[8];
        #pragma unroll
        for (int u = 0; u < 8; ++u) s[u] = colsrc[beg + j + u];
        #pragma unroll
        for (int u = 0; u < 8; ++u) r[u] = hv[(size_t)s[u] * 8 + o];
        #pragma unroll
        for (int u = 0; u < 8; ++u) addf8(acc, r[u]);
    }
    if (j + 4 <= deg) {
        int s[4]; uint2 r[4];
        #pragma unroll
        for (int u = 0; u < 4; ++u) s[u] = colsrc[beg + j + u];
        #pragma unroll
        for (int u = 0; u < 4; ++u) r[u] = hv[(size_t)s[u] * 8 + o];
        #pragma unroll
        for (int u = 0; u < 4; ++u) addf8(acc, r[u]);
        j += 4;
    }
    for (; j < deg; ++j) {
        int s = colsrc[beg + j];
        addf8(acc, hv[(size_t)s * 8 + o]);
    }
}

// ---- layer-1 agg + ReLU + in-register GEMM2: hm2' = (relu(di*sum+b1)@W2)*di -> fp8 ----

__global__ __launch_bounds__(256) void k_agg1_g2(const unsigned char* __restrict__ hm,
                                                 const int* __restrict__ rowbeg,
                                                 const int* __restrict__ rowdeg,
                                                 const ushort* __restrict__ colsrc,
                                                 const float* __restrict__ dinv,
                                                 const float* __restrict__ b1,
                                                 const float* __restrict__ W2,
                                                 unsigned char* __restrict__ outp) {
    __shared__ float Wl[64][64];
    {
        const float4* Wv = (const float4*)W2;
        float4* Wlv = (float4*)&Wl[0][0];
        #pragma unroll
        for (int i = 0; i < 4; ++i) Wlv[threadIdx.x + 256 * i] = Wv[threadIdx.x + 256 * i];
    }
    __syncthreads();
    int lane = threadIdx.x & 63;
    int wid = threadIdx.x >> 6;
    int node = (blockIdx.x * 4 + wid) * 8 + (lane >> 3);
    int o = lane & 7;
    if (node < N_NODES) {
        float acc[8];
        #pragma unroll
        for (int i = 0; i < 8; ++i) acc[i] = 0.f;
        const uint2* hv = (const uint2*)hm;
        addf8(acc, hv[(size_t)node * 8 + o]);               // self (pre-scaled)
        agg_core(hm, colsrc, rowbeg[node], rowdeg[node], o, acc);
        float di = dinv[node];
        const float4* b4 = (const float4*)b1;
        float4 bl = b4[o * 2], bh = b4[o * 2 + 1];
        float h1[8];
        h1[0] = fmaxf(di * acc[0] + bl.x, 0.f);
        h1[1] = fmaxf(di * acc[1] + bl.y, 0.f);
        h1[2] = fmaxf(di * acc[2] + bl.z, 0.f);
        h1[3] = fmaxf(di * acc[3] + bl.w, 0.f);
        h1[4] = fmaxf(di * acc[4] + bh.x, 0.f);
        h1[5] = fmaxf(di * acc[5] + bh.y, 0.f);
        h1[6] = fmaxf(di * acc[6] + bh.z, 0.f);
        h1[7] = fmaxf(di * acc[7] + bh.w, 0.f);
        float oa[8];
        #pragma unroll
        for (int i = 0; i < 8; ++i) oa[i] = 0.f;
        int gbase = lane & 56;
        #pragma unroll
        for (int g = 0; g < 8; ++g) {
            #pragma unroll
            for (int j = 0; j < 8; ++j) {
                float hk = __shfl(h1[j], gbase | g, 64);    // h1[g*8+j] of this node
                const float4 w0 = *(const float4*)&Wl[g * 8 + j][o * 8];
                const float4 w1 = *(const float4*)&Wl[g * 8 + j][o * 8 + 4];
                oa[0] += hk * w0.x; oa[1] += hk * w0.y;
                oa[2] += hk * w0.z; oa[3] += hk * w0.w;
                oa[4] += hk * w1.x; oa[5] += hk * w1.y;
                oa[6] += hk * w1.z; oa[7] += hk * w1.w;
            }
        }
        uint2 st;
        st.x = pack_fp8x4(oa[0] * di, oa[1] * di, oa[2] * di, oa[3] * di);
        st.y = pack_fp8x4(oa[4] * di, oa[5] * di, oa[6] * di, oa[7] * di);
        *(uint2*)(outp + (size_t)node * D_FEAT + o * 8) = st;
    }
}

// ---- layer-2 agg + b2 + ReLU + dot(Wfc) + block partial sum ----

__global__ __launch_bounds__(256) void k_agg2_dot(const unsigned char* __restrict__ hm,
                                                  const int* __restrict__ rowbeg,
                                                  const int* __restrict__ rowdeg,
                                                  const ushort* __restrict__ colsrc,
                                                  const float* __restrict__ dinv,
                                                  const float* __restrict__ bias,
                                                  const float* __restrict__ Wfc,
                                                  float* __restrict__ partials) {
    __shared__ float red[4];
    int lane = threadIdx.x & 63;
    int wid = threadIdx.x >> 6;
    int node = (blockIdx.x * 4 + wid) * 8 + (lane >> 3);
    int o = lane & 7;
    float s = 0.f;
    if (node < N_NODES) {
        float acc[8];
        #pragma unroll
        for (int i = 0; i < 8; ++i) acc[i] = 0.f;
        const uint2* hv = (const uint2*)hm;
        addf8(acc, hv[(size_t)node * 8 + o]);
        agg_core(hm, colsrc, rowbeg[node], rowdeg[node], o, acc);
        float di = dinv[node];
        const float4* b4 = (const float4*)bias;
        const float4* w4 = (const float4*)Wfc;
        float4 bl = b4[o * 2], bh = b4[o * 2 + 1];
        float4 wl = w4[o * 2], wh = w4[o * 2 + 1];
        s  = fmaxf(di * acc[0] + bl.x, 0.f) * wl.x;
        s += fmaxf(di * acc[1] + bl.y, 0.f) * wl.y;
        s += fmaxf(di * acc[2] + bl.z, 0.f) * wl.z;
        s += fmaxf(di * acc[3] + bl.w, 0.f) * wl.w;
        s += fmaxf(di * acc[4] + bh.x, 0.f) * wh.x;
        s += fmaxf(di * acc[5] + bh.y, 0.f) * wh.y;
        s += fmaxf(di * acc[6] + bh.z, 0.f) * wh.z;
        s += fmaxf(di * acc[7] + bh.w, 0.f) * wh.w;
    }
    #pragma unroll
    for (int m = 1; m < 64; m <<= 1) s += __shfl_xor(s, m, 64);
    if (lane == 0) red[wid] = s;
    __syncthreads();
    if (threadIdx.x == 0) partials[blockIdx.x] = red[0] + red[1] + red[2] + red[3];
}

__global__ __launch_bounds__(256) void k_final(const float* __restrict__ partials,
                                               const float* __restrict__ bfc,
                                               float* __restrict__ out) {
    __shared__ float red[4];
    float s = 0.0f;
    for (int i = threadIdx.x; i < AGG_UNITS; i += 256) s += partials[i];
    #pragma unroll
    for (int off = 32; off > 0; off >>= 1) s += __shfl_down(s, off, 64);
    if ((threadIdx.x & 63) == 0) red[threadIdx.x >> 6] = s;
    __syncthreads();
    if (threadIdx.x == 0) {
        float t = red[0] + red[1] + red[2] + red[3];
        float z = t / (float)N_NODES + bfc[0];
        out[0] = 1.0f / (1.0f + expf(-z));
    }
}

// ---------------- launcher ----------------

extern "C" void kernel_launch(void* const* d_in, const int* in_sizes, int n_in,
                              void* d_out, int out_size, void* d_ws, size_t ws_size,
                              hipStream_t stream) {
    const float* x   = (const float*)d_in[0];
    const int*   ei  = (const int*)d_in[1];
    const int*   src = ei;               // edge_index[0]
    const int*   dst = ei + N_EDGES;     // edge_index[1]
    const float* W1  = (const float*)d_in[2];
    const float* b1  = (const float*)d_in[3];
    const float* W2  = (const float*)d_in[4];
    const float* b2  = (const float*)d_in[5];
    const float* Wfc = (const float*)d_in[6];
    const float* bfc = (const float*)d_in[7];
    float* out = (float*)d_out;

    char* ws = (char*)d_ws;
    size_t off = 0;
    auto alloc = [&](size_t bytes) -> char* {
        char* p = ws + off;
        off += (bytes + 255) & ~(size_t)255;
        return p;
    };
    int*           gcount   = (int*)alloc((size_t)NBUCKET * 4);
    unsigned*      ebuf     = (unsigned*)alloc((size_t)NBUCKET * BCAP * 4);  // 4.8 MB
    ushort*        colsrc   = (ushort*)alloc((size_t)NBUCKET * BCAP * 2);    // 2.4 MB
    int*           rowbeg   = (int*)alloc((size_t)N_PAD * 4);
    int*           rowdeg   = (int*)alloc((size_t)N_PAD * 4);
    float*         dinv     = (float*)alloc((size_t)N_PAD * 4);
    float*         partials = (float*)alloc((size_t)AGG_UNITS * 4);
    unsigned char* bufA     = (unsigned char*)alloc((size_t)N_NODES * D_FEAT);  // fp8
    unsigned char* bufB     = (unsigned char*)alloc((size_t)N_NODES * D_FEAT);  // fp8

    // CSR build (gcount zeroed by graph memset node — cheaper than a 1-block kernel)
    hipMemsetAsync(gcount, 0, (size_t)NBUCKET * 4, stream);
    k_part     <<<PART_BLOCKS, 256, 0, stream>>>(src, dst, gcount, ebuf);
    k_p2group  <<<NBUCKET,     256, 0, stream>>>(ebuf, gcount, rowbeg, rowdeg, colsrc, dinv);

    // layer 1 GEMM: hm1' = (x@W1)*dinv (fp8)
    k_gemm_f32 <<<GEMM_BLOCKS, 256, 0, stream>>>(x, W1, dinv, (unsigned*)bufA);

    // layer-1 agg + relu + fused layer-2 GEMM -> fp8
    k_agg1_g2  <<<AGG_UNITS,   256, 0, stream>>>(bufA, rowbeg, rowdeg, colsrc, dinv, b1, W2, bufB);

    // layer-2 agg + b2 + relu + dot(Wfc) + partial mean
    k_agg2_dot <<<AGG_UNITS,   256, 0, stream>>>(bufB, rowbeg, rowdeg, colsrc, dinv, b2, Wfc, partials);

    // final: sigmoid(mean + bfc)
    k_final    <<<1,           256, 0, stream>>>(partials, bfc, out);
}